// Round 4
// baseline (2086.650 us; speedup 1.0000x reference)
//
#include <hip/hip_runtime.h>
#include <hip/hip_bf16.h>

// Problem constants
#define BB 32
#define VV 2562
#define V2 2564            // vertex count padded to multiple of 4
#define HH 192
#define CIN_ 966
#define KP1 992            // 966 padded to multiple of 32
#define PD 963
#define MROWS (BB * VV)    // 81984
#define MP (V2 * BB)       // 82048 rows, VB layout: row = u*32 + b
#define NBLK (V2 / 4)      // 641 blocks of 4 vertices (128 rows)

typedef __attribute__((ext_vector_type(8))) short short8;
typedef __attribute__((ext_vector_type(4))) float floatx4;
using bf16 = __hip_bfloat16;

static __device__ __forceinline__ float b2f(bf16 x) { return __bfloat162float(x); }
static __device__ __forceinline__ bf16  f2b(float x) { return __float2bfloat16(x); }
static __device__ __forceinline__ unsigned pack2(float a, float b) {
    union { bf16 h[2]; unsigned u; } t; t.h[0] = f2b(a); t.h[1] = f2b(b); return t.u;
}
static __device__ __forceinline__ float2 unpack2(unsigned v) {
    union { unsigned u; bf16 h[2]; } t; t.u = v;
    return make_float2(b2f(t.h[0]), b2f(t.h[1]));
}

// ---------------------------------------------------------------------------
// CSR build: adj dense [V,V] 0/1 fp32, self loops, degree <= 7. Padded
// vertices (u >= VV) get deg=0 / zeroed cols.
__global__ void k_csr(const float* __restrict__ adj, int* __restrict__ degs,
                      int* __restrict__ cols, float* __restrict__ invn) {
    int u = blockIdx.x;
    if (u >= VV) {
        if (threadIdx.x == 0) { degs[u] = 0; invn[u] = 0.f; }
        if (threadIdx.x < 8) cols[u * 8 + threadIdx.x] = 0;
        return;
    }
    __shared__ int cnt;
    if (threadIdx.x == 0) cnt = 0;
    __syncthreads();
    for (int j = threadIdx.x; j < VV; j += blockDim.x) {
        if (adj[(size_t)u * VV + j] != 0.0f) {
            int p = atomicAdd(&cnt, 1);
            if (p < 8) cols[u * 8 + p] = j;
        }
    }
    __syncthreads();
    if (threadIdx.x == 0) {
        degs[u] = (cnt < 8) ? cnt : 8;
        invn[u] = (cnt > 0) ? (1.0f / (float)cnt) : 0.0f;
    }
}

// ---------------------------------------------------------------------------
// Weight prep (fp32 -> bf16, transposed n-major): W1t[n][k] (k padded 992),
// Wmt[l][n][k].
__global__ void k_trans(const float* __restrict__ W1, const float* __restrict__ Wm,
                        bf16* __restrict__ W1t, bf16* __restrict__ Wmt) {
    int idx = blockIdx.x * 256 + threadIdx.x;
    const int n1 = HH * KP1;
    if (idx < n1) {
        int n = idx / KP1, k = idx % KP1;
        W1t[idx] = (k < CIN_) ? f2b(W1[(size_t)k * HH + n]) : f2b(0.0f);
    } else {
        int t = idx - n1;
        if (t < 12 * HH * HH) {
            int l = t / (HH * HH);
            int r = t % (HH * HH);
            int n = r / HH, k = r % HH;
            Wmt[t] = f2b(Wm[(size_t)l * HH * HH + (size_t)k * HH + n]);
        }
    }
}

// ---------------------------------------------------------------------------
// GEMM1: S1[VB row][192] = full[row][0..965] @ W1 with on-the-fly fp32->bf16
// staging (no materialized `full`). Block = 128 rows = 4 vertices. BK=32.
__global__ __launch_bounds__(256) void k_gemm1(const float* __restrict__ feat,
                                               const float* __restrict__ pooled,
                                               const bf16* __restrict__ W1t,
                                               float* __restrict__ Sout) {
    __shared__ bf16 As[128][40];
    const int tid  = threadIdx.x;
    const int w = tid >> 6, l = tid & 63;
    const int quad = l >> 4, l15 = l & 15;
    const int cl = tid & 31;            // staging col in tile
    const int rg = tid >> 5;            // staging row group 0..7 (16 rows each)
    const int ub = blockIdx.x * 4 + (rg >> 1);  // vertex for this thread's rows

    floatx4 acc[8][3];
#pragma unroll
    for (int i = 0; i < 8; i++)
#pragma unroll
        for (int j = 0; j < 3; j++) acc[i][j] = (floatx4){0.f, 0.f, 0.f, 0.f};

    for (int k0 = 0; k0 < KP1; k0 += 32) {
        __syncthreads();
        const int g = k0 + cl;
#pragma unroll
        for (int rr = 0; rr < 16; rr++) {
            int row = rg * 16 + rr;
            int b = row & 31;
            float v = 0.f;
            if (ub < VV && g < CIN_) {
                size_t rb = (size_t)b * VV + ub;
                v = (g < 3) ? feat[rb * 3 + g] : pooled[rb * PD + (g - 3)];
            }
            As[row][cl] = f2b(v);
        }
        __syncthreads();
        short8 bfr[3];
#pragma unroll
        for (int nt = 0; nt < 3; nt++)
            bfr[nt] = *(const short8*)(W1t + (size_t)(w * 48 + nt * 16 + l15) * KP1 + k0 + quad * 8);
#pragma unroll
        for (int mt = 0; mt < 8; mt++) {
            short8 afr = *(const short8*)(&As[mt * 16 + l15][quad * 8]);
#pragma unroll
            for (int nt = 0; nt < 3; nt++)
                acc[mt][nt] = __builtin_amdgcn_mfma_f32_16x16x32_bf16(afr, bfr[nt], acc[mt][nt], 0, 0, 0);
        }
    }
    const size_t m0 = (size_t)blockIdx.x * 128;
#pragma unroll
    for (int mt = 0; mt < 8; mt++)
#pragma unroll
        for (int nt = 0; nt < 3; nt++) {
            int n = w * 48 + nt * 16 + l15;
#pragma unroll
            for (int r = 0; r < 4; r++)
                Sout[(m0 + mt * 16 + quad * 4 + r) * HH + n] = acc[mt][nt][r];
        }
}

// ---------------------------------------------------------------------------
// Fused layer: {sparse-agg of S_prev + bias + BN(per-vertex, wave-local) +
// relu (+residual)} -> A-tile (bf16, LDS) -> GEMM with next layer's weight.
// Block = 4 vertices (128 VB rows); wave w owns vertex blk*4+w (its 6144
// values live entirely in that wave -> BN reduce is wave-local, no barrier).
// MODE 0: x -> A-tile.              (S_{l+1} = x @ W)
// MODE 1: feats = (full[:,:192]+x)/2, write featsF, A = feats.
// MODE 2: feats = (featsF+x)/2, rw featsF, A = feats.
// MODE 3: feats final: write d_out (BV layout) + SC = feats @ W15 (no Sout).
template <int MODE>
__global__ __launch_bounds__(256) void k_fused(
    const float* __restrict__ Sin,
    const int* __restrict__ degs, const int* __restrict__ cols, const float* __restrict__ invn,
    const float* __restrict__ bias, const float* __restrict__ gamma, const float* __restrict__ beta,
    const float* __restrict__ feat, const float* __restrict__ pooled,
    float* __restrict__ featsF,
    const bf16* __restrict__ Bt, float* __restrict__ Sout,
    const float* __restrict__ W15, float* __restrict__ SC, float* __restrict__ outF) {
    __shared__ bf16 At[128][200];      // A-tile; +8 pad -> only 2-way LDS aliasing
    const int tid = threadIdx.x;
    const int w = tid >> 6, l = tid & 63;
    const int u = blockIdx.x * 4 + w;
    const int uc = (u < VV) ? u : (VV - 1);  // clamp for gamma/beta reads

    const int deg = degs[u];
    int vc[8]; float vi[8];
#pragma unroll
    for (int j = 0; j < 8; j++) {
        if (j < deg) { vc[j] = cols[u * 8 + j]; vi[j] = invn[vc[j]]; }
        else         { vc[j] = 0;               vi[j] = 0.0f; }
    }
    const float* Su = Sin + (size_t)u * (32 * HH);

    // phase 1: gather y = concat(S[u][64:], agg(S[nbr][:64])) + bias; stats.
    float sum = 0.f, ss = 0.f;
    for (int i = 0; i < 48; i++) {
        int e = 2 * l + 128 * i;       // even element index, pairs (e, e+1)
        int b = e / HH, c = e - b * HH;
        float y0, y1;
        if (c < 128) {
            float2 s = *(const float2*)(Su + b * HH + 64 + c);
            y0 = s.x; y1 = s.y;
        } else {
            int d = c - 128;
            y0 = 0.f; y1 = 0.f;
#pragma unroll
            for (int j = 0; j < 8; j++) {
                float2 s = *(const float2*)(Sin + ((size_t)vc[j] * 32 + b) * HH + d);
                y0 += vi[j] * s.x; y1 += vi[j] * s.y;
            }
        }
        float2 bi = *(const float2*)(bias + c);
        y0 += bi.x; y1 += bi.y;
        sum += y0 + y1; ss += y0 * y0 + y1 * y1;
        *(unsigned*)&At[w * 32 + b][c] = pack2(y0, y1);
    }
    // wave-local BN stats (vertex == wave)
#pragma unroll
    for (int off = 32; off; off >>= 1) {
        sum += __shfl_down(sum, off, 64);
        ss  += __shfl_down(ss,  off, 64);
    }
    sum = __shfl(sum, 0, 64); ss = __shfl(ss, 0, 64);
    const float mean = sum * (1.f / 6144.f);
    float var = ss * (1.f / 6144.f) - mean * mean;
    var = fmaxf(var, 0.f);
    const float rstd = rsqrtf(var + 1e-5f);
    const float ag = gamma[uc] * rstd;
    const float bo = beta[uc] - mean * ag;

    // phase 2: affine+relu (+residual), rewrite A-tile (lane-private cells)
    for (int i = 0; i < 48; i++) {
        int e = 2 * l + 128 * i;
        int b = e / HH, c = e - b * HH;
        int row = w * 32 + b;
        float2 y = unpack2(*(unsigned*)&At[row][c]);
        float x0 = fmaxf(ag * y.x + bo, 0.f);
        float x1 = fmaxf(ag * y.y + bo, 0.f);
        if constexpr (MODE == 1) {
            float f0 = 0.f, f1 = 0.f;
            if (u < VV) {
                size_t rb = (size_t)b * VV + u;
                f0 = (c     < 3) ? feat[rb * 3 + c]     : pooled[rb * PD + (c - 3)];
                f1 = (c + 1 < 3) ? feat[rb * 3 + c + 1] : pooled[rb * PD + (c + 1 - 3)];
            }
            x0 = (f0 + x0) * 0.5f; x1 = (f1 + x1) * 0.5f;
            *(float2*)(featsF + ((size_t)u * 32 + b) * HH + c) = make_float2(x0, x1);
        }
        if constexpr (MODE == 2 || MODE == 3) {
            size_t gi = ((size_t)u * 32 + b) * HH + c;
            float2 f = *(const float2*)(featsF + gi);
            x0 = (f.x + x0) * 0.5f; x1 = (f.y + x1) * 0.5f;
            if constexpr (MODE == 2) *(float2*)(featsF + gi) = make_float2(x0, x1);
            if constexpr (MODE == 3) {
                if (u < VV)
                    *(float2*)(outF + ((size_t)b * VV + u) * HH + c) = make_float2(x0, x1);
            }
        }
        *(unsigned*)&At[row][c] = pack2(x0, x1);
    }
    __syncthreads();

    if constexpr (MODE < 3) {
        // phase 3: 128x192 @ 192x192 GEMM from LDS A-tile
        const int quad = l >> 4, l15 = l & 15;
        floatx4 acc[8][3];
#pragma unroll
        for (int i = 0; i < 8; i++)
#pragma unroll
            for (int j = 0; j < 3; j++) acc[i][j] = (floatx4){0.f, 0.f, 0.f, 0.f};
#pragma unroll
        for (int k0 = 0; k0 < HH; k0 += 32) {
            short8 bfr[3];
#pragma unroll
            for (int nt = 0; nt < 3; nt++)
                bfr[nt] = *(const short8*)(Bt + (size_t)(w * 48 + nt * 16 + l15) * HH + k0 + quad * 8);
#pragma unroll
            for (int mt = 0; mt < 8; mt++) {
                short8 afr = *(const short8*)(&At[mt * 16 + l15][k0 + quad * 8]);
#pragma unroll
                for (int nt = 0; nt < 3; nt++)
                    acc[mt][nt] = __builtin_amdgcn_mfma_f32_16x16x32_bf16(afr, bfr[nt], acc[mt][nt], 0, 0, 0);
            }
        }
        const size_t m0 = (size_t)blockIdx.x * 128;
#pragma unroll
        for (int mt = 0; mt < 8; mt++)
#pragma unroll
            for (int nt = 0; nt < 3; nt++) {
                int n = w * 48 + nt * 16 + l15;
#pragma unroll
                for (int r = 0; r < 4; r++)
                    Sout[(m0 + mt * 16 + quad * 4 + r) * HH + n] = acc[mt][nt][r];
            }
    } else {
        // coords support: SC[row][3] = feats_tile @ W15 (192x3, scalar dots)
        const size_t m0 = (size_t)blockIdx.x * 128;
        for (int idx = tid; idx < 384; idx += 256) {
            int row = idx / 3, o = idx - (idx / 3) * 3;
            float acc = 0.f;
            for (int k = 0; k < HH; k += 2) {
                float2 y = unpack2(*(unsigned*)&At[row][k]);
                acc += y.x * W15[k * 3 + o] + y.y * W15[(k + 1) * 3 + o];
            }
            SC[(m0 + row) * 3 + o] = acc;
        }
    }
}

// ---------------------------------------------------------------------------
// coords: out[b][u][0]=SC[u][b][2]+b15[0]; out[.][1/2]=agg(SC[:,:,0/1])+b15[1/2]
__global__ void k_cagg(const float* __restrict__ SC, const int* __restrict__ degs,
                       const int* __restrict__ cols, const float* __restrict__ invn,
                       const float* __restrict__ b15, float* __restrict__ out) {
    int gid = blockIdx.x * 256 + threadIdx.x;
    if (gid >= MROWS) return;
    int b = gid / VV, u = gid - b * VV;
    int deg = degs[u];
    float s0 = 0.f, s1 = 0.f;
#pragma unroll
    for (int j = 0; j < 8; j++) {
        if (j < deg) {
            int v = cols[u * 8 + j];
            float wv = invn[v];
            s0 += wv * SC[((size_t)v * 32 + b) * 3 + 0];
            s1 += wv * SC[((size_t)v * 32 + b) * 3 + 1];
        }
    }
    out[(size_t)gid * 3 + 0] = SC[((size_t)u * 32 + b) * 3 + 2] + b15[0];
    out[(size_t)gid * 3 + 1] = s0 + b15[1];
    out[(size_t)gid * 3 + 2] = s1 + b15[2];
}

// ---------------------------------------------------------------------------
extern "C" void kernel_launch(void* const* d_in, const int* in_sizes, int n_in,
                              void* d_out, int out_size, void* d_ws, size_t ws_size,
                              hipStream_t stream) {
    const float* feat   = (const float*)d_in[0];
    const float* pooled = (const float*)d_in[1];
    const float* adj    = (const float*)d_in[2];
    const float* W1     = (const float*)d_in[3];
    const float* b1     = (const float*)d_in[4];
    const float* Wm     = (const float*)d_in[5];
    const float* bm     = (const float*)d_in[6];
    const float* W15    = (const float*)d_in[7];
    const float* b15    = (const float*)d_in[8];
    const float* gamma  = (const float*)d_in[9];
    const float* beta   = (const float*)d_in[10];
    float* outF = (float*)d_out;                    // feats [B,V,192] fp32
    float* outC = outF + (size_t)MROWS * HH;        // coords [B,V,3] fp32

    char* ws = (char*)d_ws;
    size_t off = 0;
    auto alloc = [&](size_t bytes) -> void* {
        void* p = ws + off;
        off = (off + bytes + 255) & ~(size_t)255;
        return p;
    };
    float* S_a    = (float*)alloc((size_t)MP * HH * 4);   // 63 MB, S_odd
    float* S_b    = (float*)alloc((size_t)MP * HH * 4);   // 63 MB, S_even
    float* featsF = (float*)alloc((size_t)MP * HH * 4);   // 63 MB, VB layout
    bf16*  W1t    = (bf16*)alloc((size_t)HH * KP1 * 2);
    bf16*  Wmt    = (bf16*)alloc((size_t)12 * HH * HH * 2);
    float* SC     = (float*)alloc((size_t)MP * 3 * 4);
    int*   degs   = (int*)alloc(V2 * 4);
    int*   colsp  = (int*)alloc(V2 * 8 * 4);
    float* invn   = (float*)alloc(V2 * 4);
    (void)ws_size; (void)in_sizes; (void)n_in; (void)out_size;

    k_csr<<<V2, 256, 0, stream>>>(adj, degs, colsp, invn);
    int ntr = (HH * KP1 + 12 * HH * HH + 255) / 256;
    k_trans<<<ntr, 256, 0, stream>>>(W1, Wm, W1t, Wmt);

    // GEMM1 (fused input staging): S1 -> S_a
    k_gemm1<<<NBLK, 256, 0, stream>>>(feat, pooled, W1t, S_a);
    // BN(γ0,b1) + GEMM(Wm0): S2 -> S_b
    k_fused<0><<<NBLK, 256, 0, stream>>>(S_a, degs, colsp, invn, b1,
                                         gamma, beta, nullptr, nullptr, nullptr,
                                         Wmt, S_b, nullptr, nullptr, nullptr);
    // BN(γ1,bm0) + feats init + GEMM(Wm1): S3 -> S_a
    k_fused<1><<<NBLK, 256, 0, stream>>>(S_b, degs, colsp, invn, bm,
                                         gamma + VV, beta + VV, feat, pooled, featsF,
                                         Wmt + (size_t)1 * HH * HH, S_a, nullptr, nullptr, nullptr);
    // five residual pairs
    for (int i = 0; i < 5; i++) {
        int la = 2 * i + 1, lb = 2 * i + 2;
        k_fused<0><<<NBLK, 256, 0, stream>>>(S_a, degs, colsp, invn, bm + la * HH,
                                             gamma + (size_t)(la + 1) * VV, beta + (size_t)(la + 1) * VV,
                                             nullptr, nullptr, nullptr,
                                             Wmt + (size_t)(la + 1) * HH * HH, S_b,
                                             nullptr, nullptr, nullptr);
        k_fused<2><<<NBLK, 256, 0, stream>>>(S_b, degs, colsp, invn, bm + lb * HH,
                                             gamma + (size_t)(lb + 1) * VV, beta + (size_t)(lb + 1) * VV,
                                             nullptr, nullptr, featsF,
                                             Wmt + (size_t)(lb + 1) * HH * HH, S_a,
                                             nullptr, nullptr, nullptr);
    }
    // BN(γ12,bm11) + final residual -> d_out feats + SC = feats@W15
    k_fused<3><<<NBLK, 256, 0, stream>>>(S_a, degs, colsp, invn, bm + 11 * HH,
                                         gamma + (size_t)12 * VV, beta + (size_t)12 * VV,
                                         nullptr, nullptr, featsF,
                                         nullptr, nullptr, W15, SC, outF);
    // coords
    k_cagg<<<(MROWS + 255) / 256, 256, 0, stream>>>(SC, degs, colsp, invn, b15, outC);
}